// Round 6
// baseline (59665.735 us; speedup 1.0000x reference)
//
#include <hip/hip_runtime.h>
#include <cstdint>

// B=64 S=1024 D_IN=256 D_HID=512 D_LAT=128, GRU: 128->256->128, out 2
#define TOKENS 65536

// ---------------- ws layout (bytes), all f32 ----------------
#define WS_XL   0ULL
#define WS_HENC 67108864ULL
#define WS_GI0  67108864ULL
#define WS_Z    167772160ULL
#define WS_MUS  201326592ULL
#define WS_MUT  201327104ULL
#define WS_NEED 201327616ULL

// ---------------- prep: fold BN into scale/shift ----------------
__global__ void k_prep(const float* __restrict__ bmu, const float* __restrict__ bng,
                       const float* __restrict__ bnb, const float* __restrict__ bnrm,
                       const float* __restrict__ bnrv,
                       float* __restrict__ mus, float* __restrict__ mut)
{
    int j = threadIdx.x;
    if (j < 128) {
        float s = bng[j] / sqrtf(bnrv[j] + 1e-5f);
        mus[j] = s;
        mut[j] = bmu[j] * s + bnb[j] - bnrm[j] * s;
    }
}

// ---------------- xl = log(softplus(x)), f32 ----------------
__global__ void k_xl(const float* __restrict__ x, float* __restrict__ xl, int n4)
{
    int i = blockIdx.x * blockDim.x + threadIdx.x;
    if (i >= n4) return;
    float4 v = ((const float4*)x)[i];
    float4 o;
    o.x = logf(v.x > 20.f ? v.x : log1pf(expf(v.x)));
    o.y = logf(v.y > 20.f ? v.y : log1pf(expf(v.y)));
    o.z = logf(v.z > 20.f ? v.z : log1pf(expf(v.z)));
    o.w = logf(v.w > 20.f ? v.w : log1pf(expf(v.w)));
    ((float4*)xl)[i] = o;
}

// ---------------- z = mu + eps*exp(0.5*logvar), f32 ----------------
__global__ void k_z(const float* __restrict__ mu, const float* __restrict__ lv,
                    const float* __restrict__ eps, float* __restrict__ Z, int n4)
{
    int i = blockIdx.x * blockDim.x + threadIdx.x;
    if (i >= n4) return;
    float4 m = ((const float4*)mu)[i];
    float4 l = ((const float4*)lv)[i];
    float4 e = ((const float4*)eps)[i];
    float4 z;
    z.x = m.x + e.x * expf(0.5f * l.x);
    z.y = m.y + e.y * expf(0.5f * l.y);
    z.z = m.z + e.z * expf(0.5f * l.z);
    z.w = m.w + e.w * expf(0.5f * l.w);
    ((float4*)Z)[i] = z;
}

// ---------------- f32 tiled GEMM: C[m,n] = epi(acc*s[n] + t[n]) ----------------
template<int EPI>
__global__ __launch_bounds__(256) void k_gemm_f32(
    const float* __restrict__ A, const float* __restrict__ W,
    const float* __restrict__ svec, const float* __restrict__ tvec,
    float* __restrict__ C, int N, int K, int a_off)
{
    __shared__ float As[32][132];
    __shared__ float Ws[32][132];
    const int tid = threadIdx.x;
    const int tx = tid & 15, ty = tid >> 4;
    const int m0 = blockIdx.x * 128;
    const int n0 = blockIdx.y * 128;
    float acc[8][8];
#pragma unroll
    for (int i = 0; i < 8; ++i)
#pragma unroll
        for (int j = 0; j < 8; ++j) acc[i][j] = 0.f;

    for (int k0 = 0; k0 < K; k0 += 32) {
#pragma unroll
        for (int it = 0; it < 4; ++it) {
            int id = tid + 256 * it;
            int r = id >> 3, c4 = id & 7;
            float4 av = *(const float4*)(A + (size_t)(m0 + a_off + r) * K + k0 + c4 * 4);
            float4 wv = *(const float4*)(W + (size_t)(n0 + r) * K + k0 + c4 * 4);
            As[c4*4+0][r] = av.x; As[c4*4+1][r] = av.y; As[c4*4+2][r] = av.z; As[c4*4+3][r] = av.w;
            Ws[c4*4+0][r] = wv.x; Ws[c4*4+1][r] = wv.y; Ws[c4*4+2][r] = wv.z; Ws[c4*4+3][r] = wv.w;
        }
        __syncthreads();
#pragma unroll
        for (int k = 0; k < 32; ++k) {
            float4 a0 = *(const float4*)&As[k][ty*8];
            float4 a1 = *(const float4*)&As[k][ty*8+4];
            float4 w0 = *(const float4*)&Ws[k][tx*8];
            float4 w1 = *(const float4*)&Ws[k][tx*8+4];
            float ar[8] = {a0.x,a0.y,a0.z,a0.w,a1.x,a1.y,a1.z,a1.w};
            float wr[8] = {w0.x,w0.y,w0.z,w0.w,w1.x,w1.y,w1.z,w1.w};
#pragma unroll
            for (int i = 0; i < 8; ++i)
#pragma unroll
                for (int j = 0; j < 8; ++j) acc[i][j] += ar[i] * wr[j];
        }
        __syncthreads();
    }
#pragma unroll
    for (int i = 0; i < 8; ++i) {
        size_t m = (size_t)m0 + ty*8 + i;
#pragma unroll
        for (int j4 = 0; j4 < 2; ++j4) {
            float o[4];
#pragma unroll
            for (int j = 0; j < 4; ++j) {
                int col = n0 + tx*8 + j4*4 + j;
                float v = acc[i][j4*4+j];
                if (svec) v *= svec[col];
                v += tvec[col];
                if constexpr (EPI == 1) v = fmaxf(v, 0.f);
                if constexpr (EPI == 2) v = fminf(fmaxf(v, -10.f), 10.f);
                if constexpr (EPI == 3) v = expf(v);
                o[j] = v;
            }
            *(float4*)(C + m * N + n0 + tx*8 + j4*4) = *(float4*)o;
        }
    }
}

// ---------------- scan layer 0: f32; 32 blocks x 768 threads ----------------
// waves_per_eu(3,3): pins occupancy target at 3 waves/SIMD -> 170-VGPR budget,
// so the RA keeps the pinned 28 weight groups (112 VGPR) resident instead of
// sinking the loads into the time loop (round-4/5 failure: 84 VGPR + per-step
// re-stream of 1KB/row => ~14us/step of serialized L2 latency).
// Accumulation order: groups ascending, x->a0 y->a1 z->a2 w->a3 — identical
// to round 4 regardless of the reg/stream split point (bit-exact sums).
#define PIN0 28
__global__ __launch_bounds__(768)
__attribute__((amdgpu_waves_per_eu(3, 3)))
void k_scan0(
    const float* __restrict__ gi0, const float* wh0,
    const float* __restrict__ bhh0,
    const float* __restrict__ lg0, const float* __restrict__ lb0,
    float* __restrict__ h0s, int b_off)
{
    const int b = blockIdx.x;
    const int tid = threadIdx.x;
    const int lane = tid & 63;
    const int wv = tid >> 6;

    __shared__ float s_h[256];
    __shared__ float s_g[768];
    __shared__ float s_r1[4], s_r2[4];

    float4 wr[PIN0];
    {
        const float4* p = (const float4*)(wh0 + (size_t)tid * 256);
#pragma unroll
        for (int i = 0; i < PIN0; ++i) wr[i] = p[i];
    }
    const float4* wg = (const float4*)(wh0 + (size_t)tid * 256) + PIN0;
    const float bA = bhh0[tid];
    float gv = 1.f, bv = 0.f, hold = 0.f;
    if (tid < 256) { gv = lg0[tid]; bv = lb0[tid]; s_h[tid] = 0.f; }
    __syncthreads();

    const float* gbase = gi0 + (size_t)b * 1024 * 768;
    float* hb = h0s + (size_t)(b + b_off) * 1024 * 256;

    for (int t = 0; t < 1024; ++t) {
        const float* gt = gbase + (size_t)t * 768;
        float gr = 0.f, gz = 0.f, gn = 0.f;
        if (tid < 256) { gr = gt[tid]; gz = gt[tid + 256]; gn = gt[tid + 512]; }
        float a0 = bA, a1 = 0.f, a2 = 0.f, a3 = 0.f;
        const float4* H = (const float4*)s_h;
#pragma unroll
        for (int i = 0; i < PIN0; ++i) {
            float4 h4 = H[i];
            a0 += wr[i].x * h4.x; a1 += wr[i].y * h4.y;
            a2 += wr[i].z * h4.z; a3 += wr[i].w * h4.w;
        }
        // streamed tail: 36 groups, explicit 4-deep prefetch pipeline
        {
            float4 p0 = wg[0], p1 = wg[1], p2 = wg[2], p3 = wg[3];
#pragma unroll
            for (int i = 0; i < 64 - PIN0; i += 4) {
                float4 c0 = p0, c1 = p1, c2 = p2, c3 = p3;
                if (i + 4 < 64 - PIN0) {
                    p0 = wg[i+4]; p1 = wg[i+5]; p2 = wg[i+6]; p3 = wg[i+7];
                }
                { float4 h4 = H[PIN0+i+0];
                  a0 += c0.x*h4.x; a1 += c0.y*h4.y; a2 += c0.z*h4.z; a3 += c0.w*h4.w; }
                { float4 h4 = H[PIN0+i+1];
                  a0 += c1.x*h4.x; a1 += c1.y*h4.y; a2 += c1.z*h4.z; a3 += c1.w*h4.w; }
                { float4 h4 = H[PIN0+i+2];
                  a0 += c2.x*h4.x; a1 += c2.y*h4.y; a2 += c2.z*h4.z; a3 += c2.w*h4.w; }
                { float4 h4 = H[PIN0+i+3];
                  a0 += c3.x*h4.x; a1 += c3.y*h4.y; a2 += c3.z*h4.z; a3 += c3.w*h4.w; }
            }
        }
        s_g[tid] = (a0 + a1) + (a2 + a3);
        __syncthreads();
        // gates + mean-reduction
        float hn = 0.f;
        if (tid < 256) {
            float r  = 1.f / (1.f + expf(-(gr + s_g[tid])));
            float zg = 1.f / (1.f + expf(-(gz + s_g[tid + 256])));
            float nn = tanhf(gn + r * s_g[tid + 512]);
            hn = (1.f - zg) * nn + zg * hold;
            float sum = hn;
#pragma unroll
            for (int o = 32; o > 0; o >>= 1) sum += __shfl_xor(sum, o);
            if (lane == 0) s_r1[wv] = sum;
        }
        __syncthreads();
        // two-pass variance
        float d = 0.f;
        if (tid < 256) {
            float m = (s_r1[0] + s_r1[1] + s_r1[2] + s_r1[3]) * (1.f / 256.f);
            d = hn - m;
            float ss = d * d;
#pragma unroll
            for (int o = 32; o > 0; o >>= 1) ss += __shfl_xor(ss, o);
            if (lane == 0) s_r2[wv] = ss;
        }
        __syncthreads();
        if (tid < 256) {
            float va = (s_r2[0] + s_r2[1] + s_r2[2] + s_r2[3]) * (1.f / 256.f);
            float rs = 1.f / sqrtf(va + 1e-5f);
            float hl = d * rs * gv + bv;
            hold = hl;
            s_h[tid] = hl;
            hb[(size_t)t * 256 + tid] = hl;
        }
        __syncthreads();
    }
}

// ---------------- scan layer 1: f32; 64 blocks x 768 threads ----------------
#define PIN1 28
__global__ __launch_bounds__(768)
__attribute__((amdgpu_waves_per_eu(3, 3)))
void k_scan1(
    const float* __restrict__ h0s, const float* wi1, const float* wh1,
    const float* __restrict__ bih1, const float* __restrict__ bhh1,
    const float* __restrict__ lg1, const float* __restrict__ lb1,
    const float* __restrict__ fcW, const float* __restrict__ fcb,
    float* __restrict__ vout)
{
    const int b = blockIdx.x;
    const int tid = threadIdx.x;
    const int lane = tid & 63;
    const int wv = tid >> 6;

    __shared__ float s_x[256];
    __shared__ float s_h[128];
    __shared__ float s_g[768];
    __shared__ float s_r1[2], s_r2[2];

    float4 wr[32];
    const float4* wg = nullptr;
    float bB;
    if (tid < 384) {
        const float4* p = (const float4*)(wi1 + (size_t)tid * 256);
#pragma unroll
        for (int i = 0; i < PIN1; ++i) wr[i] = p[i];
        wg = p + PIN1;
        bB = bih1[tid];
    } else {
        const float4* p = (const float4*)(wh1 + (size_t)(tid - 384) * 128);
#pragma unroll
        for (int i = 0; i < 32; ++i) wr[i] = p[i];
        bB = bhh1[tid - 384];
    }
    float gv = 1.f, bv = 0.f, hold = 0.f;
    if (tid < 128) { gv = lg1[tid]; bv = lb1[tid]; s_h[tid] = 0.f; }
    __syncthreads();

    const float4* xb = (const float4*)(h0s + (size_t)b * 1024 * 256);

    for (int t = 0; t < 1024; ++t) {
        if (tid < 64) ((float4*)s_x)[tid] = xb[(size_t)t * 64 + tid];
        __syncthreads();
        float a0 = bB, a1 = 0.f, a2 = 0.f, a3 = 0.f;
        if (tid < 384) {
            const float4* X = (const float4*)s_x;
#pragma unroll
            for (int i = 0; i < PIN1; ++i) {
                float4 h4 = X[i];
                a0 += wr[i].x * h4.x; a1 += wr[i].y * h4.y;
                a2 += wr[i].z * h4.z; a3 += wr[i].w * h4.w;
            }
            float4 p0 = wg[0], p1 = wg[1], p2 = wg[2], p3 = wg[3];
#pragma unroll
            for (int i = 0; i < 64 - PIN1; i += 4) {
                float4 c0 = p0, c1 = p1, c2 = p2, c3 = p3;
                if (i + 4 < 64 - PIN1) {
                    p0 = wg[i+4]; p1 = wg[i+5]; p2 = wg[i+6]; p3 = wg[i+7];
                }
                { float4 h4 = X[PIN1+i+0];
                  a0 += c0.x*h4.x; a1 += c0.y*h4.y; a2 += c0.z*h4.z; a3 += c0.w*h4.w; }
                { float4 h4 = X[PIN1+i+1];
                  a0 += c1.x*h4.x; a1 += c1.y*h4.y; a2 += c1.z*h4.z; a3 += c1.w*h4.w; }
                { float4 h4 = X[PIN1+i+2];
                  a0 += c2.x*h4.x; a1 += c2.y*h4.y; a2 += c2.z*h4.z; a3 += c2.w*h4.w; }
                { float4 h4 = X[PIN1+i+3];
                  a0 += c3.x*h4.x; a1 += c3.y*h4.y; a2 += c3.z*h4.z; a3 += c3.w*h4.w; }
            }
        } else {
            const float4* Hh = (const float4*)s_h;
#pragma unroll
            for (int i = 0; i < 32; ++i) {
                float4 h4 = Hh[i];
                a0 += wr[i].x * h4.x; a1 += wr[i].y * h4.y;
                a2 += wr[i].z * h4.z; a3 += wr[i].w * h4.w;
            }
        }
        s_g[tid] = (a0 + a1) + (a2 + a3);
        __syncthreads();
        float hn = 0.f;
        if (tid < 128) {
            float r  = 1.f / (1.f + expf(-(s_g[tid]       + s_g[384 + tid])));
            float zg = 1.f / (1.f + expf(-(s_g[128 + tid] + s_g[512 + tid])));
            float nn = tanhf(s_g[256 + tid] + r * s_g[640 + tid]);
            hn = (1.f - zg) * nn + zg * hold;
            float sum = hn;
#pragma unroll
            for (int o = 32; o > 0; o >>= 1) sum += __shfl_xor(sum, o);
            if (lane == 0) s_r1[wv] = sum;
        }
        __syncthreads();
        float d = 0.f;
        if (tid < 128) {
            float m = (s_r1[0] + s_r1[1]) * (1.f / 128.f);
            d = hn - m;
            float ss = d * d;
#pragma unroll
            for (int o = 32; o > 0; o >>= 1) ss += __shfl_xor(ss, o);
            if (lane == 0) s_r2[wv] = ss;
        }
        __syncthreads();
        if (tid < 128) {
            float va = (s_r2[0] + s_r2[1]) * (1.f / 128.f);
            float rs = 1.f / sqrtf(va + 1e-5f);
            float hl = d * rs * gv + bv;
            hold = hl;
            s_h[tid] = hl;
        }
        __syncthreads();
    }
    float p0 = 0.f, p1 = 0.f;
    if (tid < 128) {
        p0 = fcW[tid] * hold;
        p1 = fcW[128 + tid] * hold;
#pragma unroll
        for (int o = 32; o > 0; o >>= 1) { p0 += __shfl_xor(p0, o); p1 += __shfl_xor(p1, o); }
        if (lane == 0) { s_r1[wv] = p0; s_r2[wv] = p1; }
    }
    __syncthreads();
    if (tid == 0) {
        vout[b * 2 + 0] = s_r1[0] + s_r1[1] + fcb[0];
        vout[b * 2 + 1] = s_r2[0] + s_r2[1] + fcb[1];
    }
}

// ---------------- launcher ----------------
extern "C" void kernel_launch(void* const* d_in, const int* in_sizes, int n_in,
                              void* d_out, int out_size, void* d_ws, size_t ws_size,
                              hipStream_t stream)
{
    const float* x     = (const float*)d_in[0];
    const float* eps   = (const float*)d_in[1];
    const float* W1lv  = (const float*)d_in[2];
    const float* b1lv  = (const float*)d_in[3];
    const float* W2lv  = (const float*)d_in[4];
    const float* b2lv  = (const float*)d_in[5];
    const float* Wmu   = (const float*)d_in[6];
    const float* bmu   = (const float*)d_in[7];
    const float* bn_g  = (const float*)d_in[8];
    const float* bn_b  = (const float*)d_in[9];
    const float* bn_rm = (const float*)d_in[10];
    const float* bn_rv = (const float*)d_in[11];
    const float* Wdec  = (const float*)d_in[12];
    const float* bdec  = (const float*)d_in[13];
    const float* Wih0  = (const float*)d_in[14];
    const float* Whh0  = (const float*)d_in[15];
    const float* bih0  = (const float*)d_in[16];
    const float* bhh0  = (const float*)d_in[17];
    const float* Wih1  = (const float*)d_in[18];
    const float* Whh1  = (const float*)d_in[19];
    const float* bih1  = (const float*)d_in[20];
    const float* bhh1  = (const float*)d_in[21];
    const float* ln_g0 = (const float*)d_in[22];
    const float* ln_b0 = (const float*)d_in[23];
    const float* ln_g1 = (const float*)d_in[24];
    const float* ln_b1 = (const float*)d_in[25];
    const float* fc_W  = (const float*)d_in[26];
    const float* fc_b  = (const float*)d_in[27];

    float* out   = (float*)d_out;
    float* v_out = out;                                   // [64,2]
    float* xrec  = out + 128;                             // [64,1024,256]
    float* mu    = out + 128 + 16777216;                  // [64,1024,128]
    float* lv    = out + 128 + 16777216 + 8388608;        // [64,1024,128]

    if (ws_size < WS_NEED) return;  // distinctive failure: outputs stay zero
    char* ws = (char*)d_ws;
    float* XL   = (float*)(ws + WS_XL);
    float* H0S  = (float*)(ws + WS_XL);    // overlays XL (dead after mu-GEMM)
    float* HENC = (float*)(ws + WS_HENC);
    float* GI0h = (float*)(ws + WS_GI0);   // 96MB half (overlays dead HENC)
    float* Z    = (float*)(ws + WS_Z);
    float* MUS  = (float*)(ws + WS_MUS);
    float* MUT  = (float*)(ws + WS_MUT);

    k_prep<<<1, 128, 0, stream>>>(bmu, bn_g, bn_b, bn_rm, bn_rv, MUS, MUT);
    k_xl<<<16384, 256, 0, stream>>>(x, XL, 4194304);
    // encoder
    k_gemm_f32<1><<<dim3(512, 4), 256, 0, stream>>>(XL,   W1lv, nullptr, b1lv, HENC, 512, 256, 0);
    k_gemm_f32<0><<<dim3(512, 1), 256, 0, stream>>>(HENC, W2lv, nullptr, b2lv, lv,   128, 512, 0);
    k_gemm_f32<2><<<dim3(512, 1), 256, 0, stream>>>(XL,   Wmu,  MUS,     MUT,  mu,   128, 256, 0);
    // reparameterize
    k_z<<<8192, 256, 0, stream>>>(mu, lv, eps, Z, 2097152);
    // decoder
    k_gemm_f32<3><<<dim3(512, 2), 256, 0, stream>>>(Z, Wdec, nullptr, bdec, xrec, 256, 128, 0);
    // gi0 + scan layer 0, in two batch halves (GI0 f32 = 192MB doesn't fit ws whole)
    k_gemm_f32<0><<<dim3(256, 6), 256, 0, stream>>>(Z, Wih0, nullptr, bih0, GI0h, 768, 128, 0);
    k_scan0<<<32, 768, 0, stream>>>(GI0h, Whh0, bhh0, ln_g0, ln_b0, H0S, 0);
    k_gemm_f32<0><<<dim3(256, 6), 256, 0, stream>>>(Z, Wih0, nullptr, bih0, GI0h, 768, 128, 32768);
    k_scan0<<<32, 768, 0, stream>>>(GI0h, Whh0, bhh0, ln_g0, ln_b0, H0S, 32);
    // scan layer 1 + fc head
    k_scan1<<<64, 768, 0, stream>>>(H0S, Wih1, Whh1, bih1, bhh1, ln_g1, ln_b1, fc_W, fc_b, v_out);
}

// Round 7
// 22660.803 us; speedup vs baseline: 2.6330x; 2.6330x over previous
//
#include <hip/hip_runtime.h>
#include <cstdint>

// B=64 S=1024 D_IN=256 D_HID=512 D_LAT=128, GRU: 128->256->128, out 2
#define TOKENS 65536

// ---------------- ws layout (bytes), all f32 ----------------
// phase 1: XL [0,64M), HENC [64M,192M)
// phase 2: GI0 [0,192M) (overlays XL+HENC, both dead)
// tail:    exchange buffers + counters + BN fold
#define WS_XL    0ULL
#define WS_HENC  67108864ULL
#define WS_GI0   0ULL
#define WS_XBUF0 201326592ULL                    // 64*2*4*64*4 = 131072
#define WS_XBUF1 (201326592ULL + 131072ULL)      // 64*2*4*32*4 = 65536
#define WS_CNT   (201326592ULL + 196608ULL)      // 512 B (cnt0[64], cnt1[64])
#define WS_MUS   (201326592ULL + 197120ULL)
#define WS_MUT   (201326592ULL + 197632ULL)
#define WS_NEED  (201326592ULL + 198144ULL)

// ---------------- prep: fold BN into scale/shift ----------------
__global__ void k_prep(const float* __restrict__ bmu, const float* __restrict__ bng,
                       const float* __restrict__ bnb, const float* __restrict__ bnrm,
                       const float* __restrict__ bnrv,
                       float* __restrict__ mus, float* __restrict__ mut)
{
    int j = threadIdx.x;
    if (j < 128) {
        float s = bng[j] / sqrtf(bnrv[j] + 1e-5f);
        mus[j] = s;
        mut[j] = bmu[j] * s + bnb[j] - bnrm[j] * s;
    }
}

// ---------------- xl = log(softplus(x)), f32 (identical to round 4) ----------------
__global__ void k_xl(const float* __restrict__ x, float* __restrict__ xl, int n4)
{
    int i = blockIdx.x * blockDim.x + threadIdx.x;
    if (i >= n4) return;
    float4 v = ((const float4*)x)[i];
    float4 o;
    o.x = logf(v.x > 20.f ? v.x : log1pf(expf(v.x)));
    o.y = logf(v.y > 20.f ? v.y : log1pf(expf(v.y)));
    o.z = logf(v.z > 20.f ? v.z : log1pf(expf(v.z)));
    o.w = logf(v.w > 20.f ? v.w : log1pf(expf(v.w)));
    ((float4*)xl)[i] = o;
}

// ---------------- f32 tiled GEMM: C[m,n] = epi(acc*s[n] + t[n]) ----------------
// AZ=1: A-operand computed on the fly as z = mu + eps*exp(0.5*lv) (bitwise = round-4 k_z)
template<int EPI, int AZ>
__global__ __launch_bounds__(256) void k_gemm_f32(
    const float* __restrict__ A, const float* __restrict__ W,
    const float* __restrict__ svec, const float* __restrict__ tvec,
    float* __restrict__ C, int N, int K,
    const float* __restrict__ ZMU, const float* __restrict__ ZLV, const float* __restrict__ ZEP)
{
    __shared__ float As[32][132];
    __shared__ float Ws[32][132];
    const int tid = threadIdx.x;
    const int tx = tid & 15, ty = tid >> 4;
    const int m0 = blockIdx.x * 128;
    const int n0 = blockIdx.y * 128;
    float acc[8][8];
#pragma unroll
    for (int i = 0; i < 8; ++i)
#pragma unroll
        for (int j = 0; j < 8; ++j) acc[i][j] = 0.f;

    for (int k0 = 0; k0 < K; k0 += 32) {
#pragma unroll
        for (int it = 0; it < 4; ++it) {
            int id = tid + 256 * it;
            int r = id >> 3, c4 = id & 7;
            float4 av;
            if constexpr (AZ) {
                size_t idx = (size_t)(m0 + r) * K + k0 + c4 * 4;
                float4 m4 = *(const float4*)(ZMU + idx);
                float4 l4 = *(const float4*)(ZLV + idx);
                float4 e4 = *(const float4*)(ZEP + idx);
                av.x = m4.x + e4.x * expf(0.5f * l4.x);
                av.y = m4.y + e4.y * expf(0.5f * l4.y);
                av.z = m4.z + e4.z * expf(0.5f * l4.z);
                av.w = m4.w + e4.w * expf(0.5f * l4.w);
            } else {
                av = *(const float4*)(A + (size_t)(m0 + r) * K + k0 + c4 * 4);
            }
            float4 wv = *(const float4*)(W + (size_t)(n0 + r) * K + k0 + c4 * 4);
            As[c4*4+0][r] = av.x; As[c4*4+1][r] = av.y; As[c4*4+2][r] = av.z; As[c4*4+3][r] = av.w;
            Ws[c4*4+0][r] = wv.x; Ws[c4*4+1][r] = wv.y; Ws[c4*4+2][r] = wv.z; Ws[c4*4+3][r] = wv.w;
        }
        __syncthreads();
#pragma unroll
        for (int k = 0; k < 32; ++k) {
            float4 a0 = *(const float4*)&As[k][ty*8];
            float4 a1 = *(const float4*)&As[k][ty*8+4];
            float4 w0 = *(const float4*)&Ws[k][tx*8];
            float4 w1 = *(const float4*)&Ws[k][tx*8+4];
            float ar[8] = {a0.x,a0.y,a0.z,a0.w,a1.x,a1.y,a1.z,a1.w};
            float wr[8] = {w0.x,w0.y,w0.z,w0.w,w1.x,w1.y,w1.z,w1.w};
#pragma unroll
            for (int i = 0; i < 8; ++i)
#pragma unroll
                for (int j = 0; j < 8; ++j) acc[i][j] += ar[i] * wr[j];
        }
        __syncthreads();
    }
#pragma unroll
    for (int i = 0; i < 8; ++i) {
        size_t m = (size_t)m0 + ty*8 + i;
#pragma unroll
        for (int j4 = 0; j4 < 2; ++j4) {
            float o[4];
#pragma unroll
            for (int j = 0; j < 4; ++j) {
                int col = n0 + tx*8 + j4*4 + j;
                float v = acc[i][j4*4+j];
                if (svec) v *= svec[col];
                v += tvec[col];
                if constexpr (EPI == 1) v = fmaxf(v, 0.f);
                if constexpr (EPI == 2) v = fminf(fmaxf(v, -10.f), 10.f);
                if constexpr (EPI == 3) v = expf(v);
                o[j] = v;
            }
            *(float4*)(C + m * N + n0 + tx*8 + j4*4) = *(float4*)o;
        }
    }
}

// ---------------- scan layer 0: 256 blocks (4 per batch), 256 threads ----------------
// Block q of batch b owns units [64q,64q+64) -> 192 gate rows, one FULL 256-f32 row
// per dot-thread in VGPRs (no streaming). NO __restrict__ anywhere: stores may
// alias weight reads -> rematerialization of the preloaded rows is illegal.
// Cross-block exchange of pre-LN hn via parity-buffered global + agent atomics;
// LN replayed in every block with round-4's exact butterfly (bit-identical).
__global__ __launch_bounds__(256)
__attribute__((amdgpu_waves_per_eu(1, 1)))
void k_scan0(const float* gi0, const float* wh0, const float* bhh0,
             const float* lg0, const float* lb0,
             float* h0s, float* xbuf, unsigned* cnt)
{
    const int bq  = blockIdx.x;
    const int b   = bq >> 2;
    const int q   = bq & 3;
    const int tid = threadIdx.x;
    const int lane = tid & 63;
    const int wvi  = tid >> 6;

    __shared__ float s_h[256];
    __shared__ float s_g[192];
    __shared__ float s_r1[4], s_r2[4];

    int row = 0;
    if (tid < 192)
        row = (tid < 64) ? (64*q + tid)
            : (tid < 128) ? (256 + 64*q + (tid-64))
                          : (512 + 64*q + (tid-128));
    float4 wr[64];
    float bA = 0.f;
    if (tid < 192) {
        const float4* p = (const float4*)(wh0 + (size_t)row * 256);
#pragma unroll
        for (int i = 0; i < 64; ++i) wr[i] = p[i];
        bA = bhh0[row];
    }
    const float gv = lg0[tid], bv = lb0[tid];
    s_h[tid] = 0.f;
    __syncthreads();

    const float* gbase = gi0 + (size_t)b * 1024 * 768;
    float* hb = h0s + (size_t)b * 1024 * 256;
    unsigned* cb = cnt + b;

    for (int t = 0; t < 1024; ++t) {
        float gr = 0.f, gz = 0.f, gn = 0.f;
        if (tid >= 192) {               // wave 3: issue gi0 loads under waves 0-2's dots
            const float* gt = gbase + (size_t)t * 768;
            int u = 64*q + (tid - 192);
            gr = gt[u]; gz = gt[256 + u]; gn = gt[512 + u];
        } else {
            // exact round-4 dot: groups ascending, x->a0 y->a1 z->a2 w->a3, (a0+a1)+(a2+a3)
            float a0 = bA, a1 = 0.f, a2 = 0.f, a3 = 0.f;
            const float4* H = (const float4*)s_h;
#pragma unroll
            for (int i = 0; i < 64; ++i) {
                float4 h4 = H[i];
                a0 += wr[i].x * h4.x; a1 += wr[i].y * h4.y;
                a2 += wr[i].z * h4.z; a3 += wr[i].w * h4.w;
            }
            s_g[tid] = (a0 + a1) + (a2 + a3);
        }
        __syncthreads();                                  // B1
        float* xw = xbuf + (((size_t)b * 2 + (t & 1)) * 4 + q) * 64;
        if (tid >= 192) {
            int g = tid - 192;
            int u = 64*q + g;
            float r  = 1.f / (1.f + expf(-(gr + s_g[g])));
            float zg = 1.f / (1.f + expf(-(gz + s_g[64 + g])));
            float nn = tanhf(gn + r * s_g[128 + g]);
            float hn = (1.f - zg) * nn + zg * s_h[u];
            xw[g] = hn;
        }
        __syncthreads();                                  // B2: drains gate stores (vmcnt0)
        if (tid == 0) {
            __hip_atomic_fetch_add(cb, 1u, __ATOMIC_RELEASE, __HIP_MEMORY_SCOPE_AGENT);
            unsigned tgt = 4u * (unsigned)(t + 1);
            int guard = 0;
            while (__hip_atomic_load(cb, __ATOMIC_ACQUIRE, __HIP_MEMORY_SCOPE_AGENT) < tgt) {
                __builtin_amdgcn_s_sleep(8);
                if (++guard > (1 << 22)) break;           // bounded: no infinite hang
            }
        }
        __syncthreads();                                  // B3
        const float* xr = xbuf + (((size_t)b * 2 + (t & 1)) * 4) * 64;
        float hn = xr[tid];                               // [qq*64+l] == [tid]
        float sum = hn;
#pragma unroll
        for (int o = 32; o > 0; o >>= 1) sum += __shfl_xor(sum, o);
        if (lane == 0) s_r1[wvi] = sum;
        __syncthreads();
        float m = (s_r1[0] + s_r1[1] + s_r1[2] + s_r1[3]) * (1.f / 256.f);
        float d = hn - m;
        float ss = d * d;
#pragma unroll
        for (int o = 32; o > 0; o >>= 1) ss += __shfl_xor(ss, o);
        if (lane == 0) s_r2[wvi] = ss;
        __syncthreads();
        float va = (s_r2[0] + s_r2[1] + s_r2[2] + s_r2[3]) * (1.f / 256.f);
        float rs = 1.f / sqrtf(va + 1e-5f);
        float hl = d * rs * gv + bv;
        s_h[tid] = hl;
        if (q == 0) hb[(size_t)t * 256 + tid] = hl;
        __syncthreads();                                  // B4
    }
}

// ---------------- scan layer 1: 256 blocks (4 per batch), 256 threads ----------------
// Block q owns units [32q,32q+32): 96 ih rows (256 f32 resident) + 96 hh rows (128 f32).
__global__ __launch_bounds__(256)
__attribute__((amdgpu_waves_per_eu(1, 1)))
void k_scan1(const float* h0s, const float* wi1, const float* wh1,
             const float* bih1, const float* bhh1,
             const float* lg1, const float* lb1,
             const float* fcW, const float* fcb,
             float* vout, float* xbuf, unsigned* cnt)
{
    const int bq  = blockIdx.x;
    const int b   = bq >> 2;
    const int q   = bq & 3;
    const int tid = threadIdx.x;
    const int lane = tid & 63;
    const int wvi  = tid >> 6;

    __shared__ float s_x[256];
    __shared__ float s_h[128];
    __shared__ float s_gi[96];
    __shared__ float s_gh[96];
    __shared__ float s_r1[2], s_r2[2];

    float4 wr[64];
    float bB = 0.f;
    if (tid < 96) {
        int jj = tid;
        int row = (jj < 32) ? (32*q + jj) : (jj < 64) ? (128 + 32*q + (jj-32)) : (256 + 32*q + (jj-64));
        const float4* p = (const float4*)(wi1 + (size_t)row * 256);
#pragma unroll
        for (int i = 0; i < 64; ++i) wr[i] = p[i];
        bB = bih1[row];
    } else if (tid < 192) {
        int jj = tid - 96;
        int row = (jj < 32) ? (32*q + jj) : (jj < 64) ? (128 + 32*q + (jj-32)) : (256 + 32*q + (jj-64));
        const float4* p = (const float4*)(wh1 + (size_t)row * 128);
#pragma unroll
        for (int i = 0; i < 32; ++i) wr[i] = p[i];
        bB = bhh1[row];
    }
    float gv = 0.f, bv = 0.f;
    if (tid < 128) { gv = lg1[tid]; bv = lb1[tid]; s_h[tid] = 0.f; }
    const float4* xb4 = (const float4*)(h0s + (size_t)b * 1024 * 256);
    if (tid < 64) ((float4*)s_x)[tid] = xb4[tid];         // stage t=0
    __syncthreads();

    unsigned* cb = cnt + b;

    for (int t = 0; t < 1024; ++t) {
        if (tid < 96) {
            float a0 = bB, a1 = 0.f, a2 = 0.f, a3 = 0.f;
            const float4* X = (const float4*)s_x;
#pragma unroll
            for (int i = 0; i < 64; ++i) {
                float4 h4 = X[i];
                a0 += wr[i].x * h4.x; a1 += wr[i].y * h4.y;
                a2 += wr[i].z * h4.z; a3 += wr[i].w * h4.w;
            }
            s_gi[tid] = (a0 + a1) + (a2 + a3);
        } else if (tid < 192) {
            float a0 = bB, a1 = 0.f, a2 = 0.f, a3 = 0.f;
            const float4* Hh = (const float4*)s_h;
#pragma unroll
            for (int i = 0; i < 32; ++i) {
                float4 h4 = Hh[i];
                a0 += wr[i].x * h4.x; a1 += wr[i].y * h4.y;
                a2 += wr[i].z * h4.z; a3 += wr[i].w * h4.w;
            }
            s_gh[tid - 96] = (a0 + a1) + (a2 + a3);
        }
        __syncthreads();                                  // B1
        float* xw = xbuf + (((size_t)b * 2 + (t & 1)) * 4 + q) * 32;
        if (tid >= 192 && tid < 224) {
            int g = tid - 192;
            int u = 32*q + g;
            float r  = 1.f / (1.f + expf(-(s_gi[g]      + s_gh[g])));
            float zg = 1.f / (1.f + expf(-(s_gi[32 + g] + s_gh[32 + g])));
            float nn = tanhf(s_gi[64 + g] + r * s_gh[64 + g]);
            float hn = (1.f - zg) * nn + zg * s_h[u];
            xw[g] = hn;
        } else if (tid >= 224 && t + 1 < 1024) {          // stage s_x(t+1) under gates
            int k = tid - 224;
            ((float4*)s_x)[k]      = xb4[(size_t)(t+1) * 64 + k];
            ((float4*)s_x)[k + 32] = xb4[(size_t)(t+1) * 64 + k + 32];
        }
        __syncthreads();                                  // B2
        if (tid == 0) {
            __hip_atomic_fetch_add(cb, 1u, __ATOMIC_RELEASE, __HIP_MEMORY_SCOPE_AGENT);
            unsigned tgt = 4u * (unsigned)(t + 1);
            int guard = 0;
            while (__hip_atomic_load(cb, __ATOMIC_ACQUIRE, __HIP_MEMORY_SCOPE_AGENT) < tgt) {
                __builtin_amdgcn_s_sleep(8);
                if (++guard > (1 << 22)) break;
            }
        }
        __syncthreads();                                  // B3
        const float* xr = xbuf + (((size_t)b * 2 + (t & 1)) * 4) * 32;
        float hn = 0.f, d = 0.f;
        if (tid < 128) {
            hn = xr[tid];                                 // [qq*32+l] == [tid]
            float sum = hn;
#pragma unroll
            for (int o = 32; o > 0; o >>= 1) sum += __shfl_xor(sum, o);
            if (lane == 0) s_r1[wvi] = sum;
        }
        __syncthreads();
        if (tid < 128) {
            float m = (s_r1[0] + s_r1[1]) * (1.f / 128.f);
            d = hn - m;
            float ss = d * d;
#pragma unroll
            for (int o = 32; o > 0; o >>= 1) ss += __shfl_xor(ss, o);
            if (lane == 0) s_r2[wvi] = ss;
        }
        __syncthreads();
        if (tid < 128) {
            float va = (s_r2[0] + s_r2[1]) * (1.f / 128.f);
            float rs = 1.f / sqrtf(va + 1e-5f);
            float hl = d * rs * gv + bv;
            s_h[tid] = hl;
        }
        __syncthreads();                                  // B4
    }
    float p0 = 0.f, p1 = 0.f;
    if (tid < 128) {
        float hold = s_h[tid];
        p0 = fcW[tid] * hold;
        p1 = fcW[128 + tid] * hold;
#pragma unroll
        for (int o = 32; o > 0; o >>= 1) { p0 += __shfl_xor(p0, o); p1 += __shfl_xor(p1, o); }
        if (lane == 0) { s_r1[wvi] = p0; s_r2[wvi] = p1; }
    }
    __syncthreads();
    if (tid == 0 && q == 0) {
        vout[b * 2 + 0] = s_r1[0] + s_r1[1] + fcb[0];
        vout[b * 2 + 1] = s_r2[0] + s_r2[1] + fcb[1];
    }
}

// ---------------- launcher ----------------
extern "C" void kernel_launch(void* const* d_in, const int* in_sizes, int n_in,
                              void* d_out, int out_size, void* d_ws, size_t ws_size,
                              hipStream_t stream)
{
    const float* x     = (const float*)d_in[0];
    const float* eps   = (const float*)d_in[1];
    const float* W1lv  = (const float*)d_in[2];
    const float* b1lv  = (const float*)d_in[3];
    const float* W2lv  = (const float*)d_in[4];
    const float* b2lv  = (const float*)d_in[5];
    const float* Wmu   = (const float*)d_in[6];
    const float* bmu   = (const float*)d_in[7];
    const float* bn_g  = (const float*)d_in[8];
    const float* bn_b  = (const float*)d_in[9];
    const float* bn_rm = (const float*)d_in[10];
    const float* bn_rv = (const float*)d_in[11];
    const float* Wdec  = (const float*)d_in[12];
    const float* bdec  = (const float*)d_in[13];
    const float* Wih0  = (const float*)d_in[14];
    const float* Whh0  = (const float*)d_in[15];
    const float* bih0  = (const float*)d_in[16];
    const float* bhh0  = (const float*)d_in[17];
    const float* Wih1  = (const float*)d_in[18];
    const float* Whh1  = (const float*)d_in[19];
    const float* bih1  = (const float*)d_in[20];
    const float* bhh1  = (const float*)d_in[21];
    const float* ln_g0 = (const float*)d_in[22];
    const float* ln_b0 = (const float*)d_in[23];
    const float* ln_g1 = (const float*)d_in[24];
    const float* ln_b1 = (const float*)d_in[25];
    const float* fc_W  = (const float*)d_in[26];
    const float* fc_b  = (const float*)d_in[27];

    float* out   = (float*)d_out;
    float* v_out = out;                                   // [64,2]
    float* xrec  = out + 128;                             // [64,1024,256]
    float* mu    = out + 128 + 16777216;                  // [64,1024,128]
    float* lv    = out + 128 + 16777216 + 8388608;        // [64,1024,128]
    float* H0S   = xrec;  // h0 stream parked in xrec slot; decoder GEMM overwrites after scan1

    if (ws_size < WS_NEED) return;  // distinctive failure: outputs stay zero
    char* ws = (char*)d_ws;
    float*    XL    = (float*)(ws + WS_XL);
    float*    HENC  = (float*)(ws + WS_HENC);
    float*    GI0   = (float*)(ws + WS_GI0);    // overlays XL+HENC (dead by then)
    float*    XBUF0 = (float*)(ws + WS_XBUF0);
    float*    XBUF1 = (float*)(ws + WS_XBUF1);
    unsigned* CNT0  = (unsigned*)(ws + WS_CNT);
    unsigned* CNT1  = CNT0 + 64;
    float*    MUS   = (float*)(ws + WS_MUS);
    float*    MUT   = (float*)(ws + WS_MUT);

    k_prep<<<1, 128, 0, stream>>>(bmu, bn_g, bn_b, bn_rm, bn_rv, MUS, MUT);
    k_xl<<<16384, 256, 0, stream>>>(x, XL, 4194304);
    // encoder
    k_gemm_f32<1,0><<<dim3(512, 4), 256, 0, stream>>>(XL,   W1lv, nullptr, b1lv, HENC, 512, 256, nullptr, nullptr, nullptr);
    k_gemm_f32<0,0><<<dim3(512, 1), 256, 0, stream>>>(HENC, W2lv, nullptr, b2lv, lv,   128, 512, nullptr, nullptr, nullptr);
    k_gemm_f32<2,0><<<dim3(512, 1), 256, 0, stream>>>(XL,   Wmu,  MUS,     MUT,  mu,   128, 256, nullptr, nullptr, nullptr);
    // gi0 GEMM with fused reparameterization (XL/HENC dead -> GI0 overlays them)
    k_gemm_f32<0,1><<<dim3(512, 6), 256, 0, stream>>>(nullptr, Wih0, nullptr, bih0, GI0, 768, 128, mu, lv, eps);
    // reset exchange counters (per launch, graph-captured)
    hipMemsetAsync(CNT0, 0, 512, stream);
    // sequential scans (4 blocks per batch row, full weight residency)
    k_scan0<<<256, 256, 0, stream>>>(GI0, Whh0, bhh0, ln_g0, ln_b0, H0S, XBUF0, CNT0);
    k_scan1<<<256, 256, 0, stream>>>(H0S, Wih1, Whh1, bih1, bhh1, ln_g1, ln_b1, fc_W, fc_b, v_out, XBUF1, CNT1);
    // decoder with fused reparameterization (overwrites H0S parking with final xrec)
    k_gemm_f32<3,1><<<dim3(512, 2), 256, 0, stream>>>(nullptr, Wdec, nullptr, bdec, xrec, 256, 128, mu, lv, eps);
}

// Round 8
// 10890.379 us; speedup vs baseline: 5.4788x; 2.0808x over previous
//
#include <hip/hip_runtime.h>
#include <cstdint>

// B=64 S=1024 D_IN=256 D_HID=512 D_LAT=128, GRU: 128->256->128, out 2
#define TOKENS 65536

// ---------------- ws layout (bytes), all f32 ----------------
#define WS_XL    0ULL
#define WS_HENC  67108864ULL
#define WS_GI0   0ULL
#define WS_XBUF0 201326592ULL                    // 64*2*4*64*4 = 131072
#define WS_XBUF1 (201326592ULL + 131072ULL)      // 64*2*4*32*4 = 65536
#define WS_CNT   (201326592ULL + 196608ULL)      // 512 B (cnt0[64], cnt1[64])
#define WS_MUS   (201326592ULL + 197120ULL)
#define WS_MUT   (201326592ULL + 197632ULL)
#define WS_NEED  (201326592ULL + 198144ULL)

// ---------------- prep: fold BN into scale/shift ----------------
__global__ void k_prep(const float* __restrict__ bmu, const float* __restrict__ bng,
                       const float* __restrict__ bnb, const float* __restrict__ bnrm,
                       const float* __restrict__ bnrv,
                       float* __restrict__ mus, float* __restrict__ mut)
{
    int j = threadIdx.x;
    if (j < 128) {
        float s = bng[j] / sqrtf(bnrv[j] + 1e-5f);
        mus[j] = s;
        mut[j] = bmu[j] * s + bnb[j] - bnrm[j] * s;
    }
}

// ---------------- xl = log(softplus(x)), f32 ----------------
__global__ void k_xl(const float* __restrict__ x, float* __restrict__ xl, int n4)
{
    int i = blockIdx.x * blockDim.x + threadIdx.x;
    if (i >= n4) return;
    float4 v = ((const float4*)x)[i];
    float4 o;
    o.x = logf(v.x > 20.f ? v.x : log1pf(expf(v.x)));
    o.y = logf(v.y > 20.f ? v.y : log1pf(expf(v.y)));
    o.z = logf(v.z > 20.f ? v.z : log1pf(expf(v.z)));
    o.w = logf(v.w > 20.f ? v.w : log1pf(expf(v.w)));
    ((float4*)xl)[i] = o;
}

// ---------------- f32 tiled GEMM: C[m,n] = epi(acc*s[n] + t[n]) ----------------
// AZ=1: A computed on the fly as z = mu + eps*exp(0.5*lv) (same expr as round 7)
template<int EPI, int AZ>
__global__ __launch_bounds__(256) void k_gemm_f32(
    const float* __restrict__ A, const float* __restrict__ W,
    const float* __restrict__ svec, const float* __restrict__ tvec,
    float* __restrict__ C, int N, int K,
    const float* __restrict__ ZMU, const float* __restrict__ ZLV, const float* __restrict__ ZEP)
{
    __shared__ float As[32][132];
    __shared__ float Ws[32][132];
    const int tid = threadIdx.x;
    const int tx = tid & 15, ty = tid >> 4;
    const int m0 = blockIdx.x * 128;
    const int n0 = blockIdx.y * 128;
    float acc[8][8];
#pragma unroll
    for (int i = 0; i < 8; ++i)
#pragma unroll
        for (int j = 0; j < 8; ++j) acc[i][j] = 0.f;

    for (int k0 = 0; k0 < K; k0 += 32) {
#pragma unroll
        for (int it = 0; it < 4; ++it) {
            int id = tid + 256 * it;
            int r = id >> 3, c4 = id & 7;
            float4 av;
            if constexpr (AZ) {
                size_t idx = (size_t)(m0 + r) * K + k0 + c4 * 4;
                float4 m4 = *(const float4*)(ZMU + idx);
                float4 l4 = *(const float4*)(ZLV + idx);
                float4 e4 = *(const float4*)(ZEP + idx);
                av.x = m4.x + e4.x * expf(0.5f * l4.x);
                av.y = m4.y + e4.y * expf(0.5f * l4.y);
                av.z = m4.z + e4.z * expf(0.5f * l4.z);
                av.w = m4.w + e4.w * expf(0.5f * l4.w);
            } else {
                av = *(const float4*)(A + (size_t)(m0 + r) * K + k0 + c4 * 4);
            }
            float4 wv = *(const float4*)(W + (size_t)(n0 + r) * K + k0 + c4 * 4);
            As[c4*4+0][r] = av.x; As[c4*4+1][r] = av.y; As[c4*4+2][r] = av.z; As[c4*4+3][r] = av.w;
            Ws[c4*4+0][r] = wv.x; Ws[c4*4+1][r] = wv.y; Ws[c4*4+2][r] = wv.z; Ws[c4*4+3][r] = wv.w;
        }
        __syncthreads();
#pragma unroll
        for (int k = 0; k < 32; ++k) {
            float4 a0 = *(const float4*)&As[k][ty*8];
            float4 a1 = *(const float4*)&As[k][ty*8+4];
            float4 w0 = *(const float4*)&Ws[k][tx*8];
            float4 w1 = *(const float4*)&Ws[k][tx*8+4];
            float ar[8] = {a0.x,a0.y,a0.z,a0.w,a1.x,a1.y,a1.z,a1.w};
            float wr[8] = {w0.x,w0.y,w0.z,w0.w,w1.x,w1.y,w1.z,w1.w};
#pragma unroll
            for (int i = 0; i < 8; ++i)
#pragma unroll
                for (int j = 0; j < 8; ++j) acc[i][j] += ar[i] * wr[j];
        }
        __syncthreads();
    }
#pragma unroll
    for (int i = 0; i < 8; ++i) {
        size_t m = (size_t)m0 + ty*8 + i;
#pragma unroll
        for (int j4 = 0; j4 < 2; ++j4) {
            float o[4];
#pragma unroll
            for (int j = 0; j < 4; ++j) {
                int col = n0 + tx*8 + j4*4 + j;
                float v = acc[i][j4*4+j];
                if (svec) v *= svec[col];
                v += tvec[col];
                if constexpr (EPI == 1) v = fmaxf(v, 0.f);
                if constexpr (EPI == 2) v = fminf(fmaxf(v, -10.f), 10.f);
                if constexpr (EPI == 3) v = expf(v);
                o[j] = v;
            }
            *(float4*)(C + m * N + n0 + tx*8 + j4*4) = *(float4*)o;
        }
    }
}

// ============ cross-block exchange: relaxed agent atomics, NO fences ============
// Agent-scope atomics bypass the (non-coherent) per-XCD L2 -> visible at LLC.
// No ACQUIRE/RELEASE: those lower to whole-L2 writeback/invalidate per step on
// multi-XCD gfx950 (round-7: FETCH 195MB, 11us/step). Ordering is done by HW
// store-completion: __syncthreads drains vmcnt for all waves before the bump.
// Poll uses fetch_add(0) (RMW executes at coherence point -> always fresh).
__device__ __forceinline__ void xstore(float* p, float v) {
    __hip_atomic_store(p, v, __ATOMIC_RELAXED, __HIP_MEMORY_SCOPE_AGENT);
}
__device__ __forceinline__ float xload(const float* p) {
    return __hip_atomic_load(p, __ATOMIC_RELAXED, __HIP_MEMORY_SCOPE_AGENT);
}
__device__ __forceinline__ void xsync(unsigned* cb, unsigned tgt) {
    asm volatile("s_waitcnt vmcnt(0)" ::: "memory");
    __hip_atomic_fetch_add(cb, 1u, __ATOMIC_RELAXED, __HIP_MEMORY_SCOPE_AGENT);
    int guard = 0;
    while (__hip_atomic_fetch_add(cb, 0u, __ATOMIC_RELAXED, __HIP_MEMORY_SCOPE_AGENT) < tgt) {
        __builtin_amdgcn_s_sleep(4);
        if (++guard > (1 << 16)) break;   // bounded: fails measurably, not a hang
    }
    asm volatile("" ::: "memory");
}

// ---------------- scan layer 0: 256 blocks (4 per batch), 256 threads ----------------
// XCD-grouping swizzle (perf heuristic only; correctness is placement-independent):
// blockIdx%8 -> XCD on MI355X round-robin, so the 4 blocks of a batch share one L2.
__global__ __launch_bounds__(256)
__attribute__((amdgpu_waves_per_eu(1, 1)))
void k_scan0(const float* gi0, const float* wh0, const float* bhh0,
             const float* lg0, const float* lb0,
             float* h0s, float* xbuf, unsigned* cnt)
{
    const int xcd  = blockIdx.x & 7;
    const int slot = blockIdx.x >> 3;       // 0..31
    const int b    = xcd * 8 + (slot >> 2); // 4 blocks of b land on one XCD
    const int q    = slot & 3;
    const int tid = threadIdx.x;
    const int lane = tid & 63;
    const int wvi  = tid >> 6;

    __shared__ float s_h[256];
    __shared__ float s_g[192];
    __shared__ float s_r1[4], s_r2[4];

    int row = 0;
    if (tid < 192)
        row = (tid < 64) ? (64*q + tid)
            : (tid < 128) ? (256 + 64*q + (tid-64))
                          : (512 + 64*q + (tid-128));
    float4 wr[64];
    float bA = 0.f;
    if (tid < 192) {
        const float4* p = (const float4*)(wh0 + (size_t)row * 256);
#pragma unroll
        for (int i = 0; i < 64; ++i) wr[i] = p[i];
        bA = bhh0[row];
    }
    const float gv = lg0[tid], bv = lb0[tid];
    s_h[tid] = 0.f;
    __syncthreads();

    const float* gbase = gi0 + (size_t)b * 1024 * 768;
    float* hb = h0s + (size_t)b * 1024 * 256;
    unsigned* cb = cnt + b;

    for (int t = 0; t < 1024; ++t) {
        float gr = 0.f, gz = 0.f, gn = 0.f;
        if (tid >= 192) {               // wave 3: issue gi0 loads under waves 0-2's dots
            const float* gt = gbase + (size_t)t * 768;
            int u = 64*q + (tid - 192);
            gr = gt[u]; gz = gt[256 + u]; gn = gt[512 + u];
        } else {
            // frozen round-4 dot: groups ascending, x->a0 y->a1 z->a2 w->a3, (a0+a1)+(a2+a3)
            float a0 = bA, a1 = 0.f, a2 = 0.f, a3 = 0.f;
            const float4* H = (const float4*)s_h;
#pragma unroll
            for (int i = 0; i < 64; ++i) {
                float4 h4 = H[i];
                a0 += wr[i].x * h4.x; a1 += wr[i].y * h4.y;
                a2 += wr[i].z * h4.z; a3 += wr[i].w * h4.w;
            }
            s_g[tid] = (a0 + a1) + (a2 + a3);
        }
        __syncthreads();                                  // B1
        float* xw = xbuf + (((size_t)b * 2 + (t & 1)) * 4 + q) * 64;
        if (tid >= 192) {
            int g = tid - 192;
            int u = 64*q + g;
            float r  = 1.f / (1.f + expf(-(gr + s_g[g])));
            float zg = 1.f / (1.f + expf(-(gz + s_g[64 + g])));
            float nn = tanhf(gn + r * s_g[128 + g]);
            float hn = (1.f - zg) * nn + zg * s_h[u];
            xstore(&xw[g], hn);
        }
        __syncthreads();                                  // B2: drains all waves' stores
        if (tid == 0) xsync(cb, 4u * (unsigned)(t + 1));
        __syncthreads();                                  // B3
        const float* xr = xbuf + (((size_t)b * 2 + (t & 1)) * 4) * 64;
        float hn = xload(&xr[tid]);
        float sum = hn;
#pragma unroll
        for (int o = 32; o > 0; o >>= 1) sum += __shfl_xor(sum, o);
        if (lane == 0) s_r1[wvi] = sum;
        __syncthreads();
        float m = (s_r1[0] + s_r1[1] + s_r1[2] + s_r1[3]) * (1.f / 256.f);
        float d = hn - m;
        float ss = d * d;
#pragma unroll
        for (int o = 32; o > 0; o >>= 1) ss += __shfl_xor(ss, o);
        if (lane == 0) s_r2[wvi] = ss;
        __syncthreads();
        float va = (s_r2[0] + s_r2[1] + s_r2[2] + s_r2[3]) * (1.f / 256.f);
        float rs = 1.f / sqrtf(va + 1e-5f);
        float hl = d * rs * gv + bv;
        s_h[tid] = hl;
        if (q == 0) hb[(size_t)t * 256 + tid] = hl;
        __syncthreads();                                  // B4
    }
}

// ---------------- scan layer 1: 256 blocks (4 per batch), 256 threads ----------------
__global__ __launch_bounds__(256)
__attribute__((amdgpu_waves_per_eu(1, 1)))
void k_scan1(const float* h0s, const float* wi1, const float* wh1,
             const float* bih1, const float* bhh1,
             const float* lg1, const float* lb1,
             const float* fcW, const float* fcb,
             float* vout, float* xbuf, unsigned* cnt)
{
    const int xcd  = blockIdx.x & 7;
    const int slot = blockIdx.x >> 3;
    const int b    = xcd * 8 + (slot >> 2);
    const int q    = slot & 3;
    const int tid = threadIdx.x;
    const int lane = tid & 63;
    const int wvi  = tid >> 6;

    __shared__ float s_x[256];
    __shared__ float s_h[128];
    __shared__ float s_gi[96];
    __shared__ float s_gh[96];
    __shared__ float s_r1[2], s_r2[2];

    float4 wr[64];
    float bB = 0.f;
    if (tid < 96) {
        int jj = tid;
        int row = (jj < 32) ? (32*q + jj) : (jj < 64) ? (128 + 32*q + (jj-32)) : (256 + 32*q + (jj-64));
        const float4* p = (const float4*)(wi1 + (size_t)row * 256);
#pragma unroll
        for (int i = 0; i < 64; ++i) wr[i] = p[i];
        bB = bih1[row];
    } else if (tid < 192) {
        int jj = tid - 96;
        int row = (jj < 32) ? (32*q + jj) : (jj < 64) ? (128 + 32*q + (jj-32)) : (256 + 32*q + (jj-64));
        const float4* p = (const float4*)(wh1 + (size_t)row * 128);
#pragma unroll
        for (int i = 0; i < 32; ++i) wr[i] = p[i];
        bB = bhh1[row];
    }
    float gv = 0.f, bv = 0.f;
    if (tid < 128) { gv = lg1[tid]; bv = lb1[tid]; s_h[tid] = 0.f; }
    const float4* xb4 = (const float4*)(h0s + (size_t)b * 1024 * 256);
    if (tid < 64) ((float4*)s_x)[tid] = xb4[tid];         // stage t=0
    __syncthreads();

    unsigned* cb = cnt + b;

    for (int t = 0; t < 1024; ++t) {
        if (tid < 96) {
            float a0 = bB, a1 = 0.f, a2 = 0.f, a3 = 0.f;
            const float4* X = (const float4*)s_x;
#pragma unroll
            for (int i = 0; i < 64; ++i) {
                float4 h4 = X[i];
                a0 += wr[i].x * h4.x; a1 += wr[i].y * h4.y;
                a2 += wr[i].z * h4.z; a3 += wr[i].w * h4.w;
            }
            s_gi[tid] = (a0 + a1) + (a2 + a3);
        } else if (tid < 192) {
            float a0 = bB, a1 = 0.f, a2 = 0.f, a3 = 0.f;
            const float4* Hh = (const float4*)s_h;
#pragma unroll
            for (int i = 0; i < 32; ++i) {
                float4 h4 = Hh[i];
                a0 += wr[i].x * h4.x; a1 += wr[i].y * h4.y;
                a2 += wr[i].z * h4.z; a3 += wr[i].w * h4.w;
            }
            s_gh[tid - 96] = (a0 + a1) + (a2 + a3);
        }
        __syncthreads();                                  // B1
        float* xw = xbuf + (((size_t)b * 2 + (t & 1)) * 4 + q) * 32;
        if (tid >= 192 && tid < 224) {
            int g = tid - 192;
            int u = 32*q + g;
            float r  = 1.f / (1.f + expf(-(s_gi[g]      + s_gh[g])));
            float zg = 1.f / (1.f + expf(-(s_gi[32 + g] + s_gh[32 + g])));
            float nn = tanhf(s_gi[64 + g] + r * s_gh[64 + g]);
            float hn = (1.f - zg) * nn + zg * s_h[u];
            xstore(&xw[g], hn);
        } else if (tid >= 224 && t + 1 < 1024) {          // stage s_x(t+1) under gates
            int k = tid - 224;
            ((float4*)s_x)[k]      = xb4[(size_t)(t+1) * 64 + k];
            ((float4*)s_x)[k + 32] = xb4[(size_t)(t+1) * 64 + k + 32];
        }
        __syncthreads();                                  // B2
        if (tid == 0) xsync(cb, 4u * (unsigned)(t + 1));
        __syncthreads();                                  // B3
        const float* xr = xbuf + (((size_t)b * 2 + (t & 1)) * 4) * 32;
        float hn = 0.f, d = 0.f;
        if (tid < 128) {
            hn = xload(&xr[tid]);
            float sum = hn;
#pragma unroll
            for (int o = 32; o > 0; o >>= 1) sum += __shfl_xor(sum, o);
            if (lane == 0) s_r1[wvi] = sum;
        }
        __syncthreads();
        if (tid < 128) {
            float m = (s_r1[0] + s_r1[1]) * (1.f / 128.f);
            d = hn - m;
            float ss = d * d;
#pragma unroll
            for (int o = 32; o > 0; o >>= 1) ss += __shfl_xor(ss, o);
            if (lane == 0) s_r2[wvi] = ss;
        }
        __syncthreads();
        if (tid < 128) {
            float va = (s_r2[0] + s_r2[1]) * (1.f / 128.f);
            float rs = 1.f / sqrtf(va + 1e-5f);
            float hl = d * rs * gv + bv;
            s_h[tid] = hl;
        }
        __syncthreads();                                  // B4
    }
    float p0 = 0.f, p1 = 0.f;
    if (tid < 128) {
        float hold = s_h[tid];
        p0 = fcW[tid] * hold;
        p1 = fcW[128 + tid] * hold;
#pragma unroll
        for (int o = 32; o > 0; o >>= 1) { p0 += __shfl_xor(p0, o); p1 += __shfl_xor(p1, o); }
        if (lane == 0) { s_r1[wvi] = p0; s_r2[wvi] = p1; }
    }
    __syncthreads();
    if (tid == 0 && q == 0) {
        vout[b * 2 + 0] = s_r1[0] + s_r1[1] + fcb[0];
        vout[b * 2 + 1] = s_r2[0] + s_r2[1] + fcb[1];
    }
}

// ---------------- launcher ----------------
extern "C" void kernel_launch(void* const* d_in, const int* in_sizes, int n_in,
                              void* d_out, int out_size, void* d_ws, size_t ws_size,
                              hipStream_t stream)
{
    const float* x     = (const float*)d_in[0];
    const float* eps   = (const float*)d_in[1];
    const float* W1lv  = (const float*)d_in[2];
    const float* b1lv  = (const float*)d_in[3];
    const float* W2lv  = (const float*)d_in[4];
    const float* b2lv  = (const float*)d_in[5];
    const float* Wmu   = (const float*)d_in[6];
    const float* bmu   = (const float*)d_in[7];
    const float* bn_g  = (const float*)d_in[8];
    const float* bn_b  = (const float*)d_in[9];
    const float* bn_rm = (const float*)d_in[10];
    const float* bn_rv = (const float*)d_in[11];
    const float* Wdec  = (const float*)d_in[12];
    const float* bdec  = (const float*)d_in[13];
    const float* Wih0  = (const float*)d_in[14];
    const float* Whh0  = (const float*)d_in[15];
    const float* bih0  = (const float*)d_in[16];
    const float* bhh0  = (const float*)d_in[17];
    const float* Wih1  = (const float*)d_in[18];
    const float* Whh1  = (const float*)d_in[19];
    const float* bih1  = (const float*)d_in[20];
    const float* bhh1  = (const float*)d_in[21];
    const float* ln_g0 = (const float*)d_in[22];
    const float* ln_b0 = (const float*)d_in[23];
    const float* ln_g1 = (const float*)d_in[24];
    const float* ln_b1 = (const float*)d_in[25];
    const float* fc_W  = (const float*)d_in[26];
    const float* fc_b  = (const float*)d_in[27];

    float* out   = (float*)d_out;
    float* v_out = out;                                   // [64,2]
    float* xrec  = out + 128;                             // [64,1024,256]
    float* mu    = out + 128 + 16777216;                  // [64,1024,128]
    float* lv    = out + 128 + 16777216 + 8388608;        // [64,1024,128]
    float* H0S   = xrec;  // h0 stream parked in xrec slot; decoder overwrites after scan1

    if (ws_size < WS_NEED) return;  // distinctive failure: outputs stay zero
    char* ws = (char*)d_ws;
    float*    XL    = (float*)(ws + WS_XL);
    float*    HENC  = (float*)(ws + WS_HENC);
    float*    GI0   = (float*)(ws + WS_GI0);    // overlays XL+HENC (dead by then)
    float*    XBUF0 = (float*)(ws + WS_XBUF0);
    float*    XBUF1 = (float*)(ws + WS_XBUF1);
    unsigned* CNT0  = (unsigned*)(ws + WS_CNT);
    unsigned* CNT1  = CNT0 + 64;
    float*    MUS   = (float*)(ws + WS_MUS);
    float*    MUT   = (float*)(ws + WS_MUT);

    k_prep<<<1, 128, 0, stream>>>(bmu, bn_g, bn_b, bn_rm, bn_rv, MUS, MUT);
    k_xl<<<16384, 256, 0, stream>>>(x, XL, 4194304);
    // encoder
    k_gemm_f32<1,0><<<dim3(512, 4), 256, 0, stream>>>(XL,   W1lv, nullptr, b1lv, HENC, 512, 256, nullptr, nullptr, nullptr);
    k_gemm_f32<0,0><<<dim3(512, 1), 256, 0, stream>>>(HENC, W2lv, nullptr, b2lv, lv,   128, 512, nullptr, nullptr, nullptr);
    k_gemm_f32<2,0><<<dim3(512, 1), 256, 0, stream>>>(XL,   Wmu,  MUS,     MUT,  mu,   128, 256, nullptr, nullptr, nullptr);
    // gi0 GEMM with fused reparameterization (XL/HENC dead -> GI0 overlays them)
    k_gemm_f32<0,1><<<dim3(512, 6), 256, 0, stream>>>(nullptr, Wih0, nullptr, bih0, GI0, 768, 128, mu, lv, eps);
    // reset exchange counters (per launch, graph-capture-safe)
    hipMemsetAsync(CNT0, 0, 512, stream);
    // sequential scans (4 blocks per batch row, full weight residency)
    k_scan0<<<256, 256, 0, stream>>>(GI0, Whh0, bhh0, ln_g0, ln_b0, H0S, XBUF0, CNT0);
    k_scan1<<<256, 256, 0, stream>>>(H0S, Wih1, Whh1, bih1, bhh1, ln_g1, ln_b1, fc_W, fc_b, v_out, XBUF1, CNT1);
    // decoder with fused reparameterization (overwrites H0S parking with final xrec)
    k_gemm_f32<3,1><<<dim3(512, 2), 256, 0, stream>>>(nullptr, Wdec, nullptr, bdec, xrec, 256, 128, mu, lv, eps);
}

// Round 9
// 8991.628 us; speedup vs baseline: 6.6357x; 1.2112x over previous
//
#include <hip/hip_runtime.h>
#include <cstdint>

// B=64 S=1024 D_IN=256 D_HID=512 D_LAT=128, GRU: 128->256->128, out 2
#define TOKENS 65536

// ---------------- ws layout (bytes), all f32 ----------------
#define WS_XL    0ULL
#define WS_HENC  67108864ULL
#define WS_GI0   0ULL
#define WS_XBUF0 201326592ULL                    // 131072 B
#define WS_XBUF1 (201326592ULL + 131072ULL)      // 65536 B
#define WS_CNT   (201326592ULL + 196608ULL)      // 2*64 counters, 256B stride = 32768 B
#define WS_MUS   (201326592ULL + 229376ULL)
#define WS_MUT   (201326592ULL + 229888ULL)
#define WS_NEED  (201326592ULL + 230400ULL)
#define CNT_STRIDE 64                            // uints; 256B line pitch per counter

// ---------------- prep: fold BN into scale/shift ----------------
__global__ void k_prep(const float* __restrict__ bmu, const float* __restrict__ bng,
                       const float* __restrict__ bnb, const float* __restrict__ bnrm,
                       const float* __restrict__ bnrv,
                       float* __restrict__ mus, float* __restrict__ mut)
{
    int j = threadIdx.x;
    if (j < 128) {
        float s = bng[j] / sqrtf(bnrv[j] + 1e-5f);
        mus[j] = s;
        mut[j] = bmu[j] * s + bnb[j] - bnrm[j] * s;
    }
}

// ---------------- xl = log(softplus(x)), f32 ----------------
__global__ void k_xl(const float* __restrict__ x, float* __restrict__ xl, int n4)
{
    int i = blockIdx.x * blockDim.x + threadIdx.x;
    if (i >= n4) return;
    float4 v = ((const float4*)x)[i];
    float4 o;
    o.x = logf(v.x > 20.f ? v.x : log1pf(expf(v.x)));
    o.y = logf(v.y > 20.f ? v.y : log1pf(expf(v.y)));
    o.z = logf(v.z > 20.f ? v.z : log1pf(expf(v.z)));
    o.w = logf(v.w > 20.f ? v.w : log1pf(expf(v.w)));
    ((float4*)xl)[i] = o;
}

// ---------------- f32 tiled GEMM: C[m,n] = epi(acc*s[n] + t[n]) ----------------
// AZ=1: A computed on the fly as z = mu + eps*exp(0.5*lv)
template<int EPI, int AZ>
__global__ __launch_bounds__(256) void k_gemm_f32(
    const float* __restrict__ A, const float* __restrict__ W,
    const float* __restrict__ svec, const float* __restrict__ tvec,
    float* __restrict__ C, int N, int K,
    const float* __restrict__ ZMU, const float* __restrict__ ZLV, const float* __restrict__ ZEP)
{
    __shared__ float As[32][132];
    __shared__ float Ws[32][132];
    const int tid = threadIdx.x;
    const int tx = tid & 15, ty = tid >> 4;
    const int m0 = blockIdx.x * 128;
    const int n0 = blockIdx.y * 128;
    float acc[8][8];
#pragma unroll
    for (int i = 0; i < 8; ++i)
#pragma unroll
        for (int j = 0; j < 8; ++j) acc[i][j] = 0.f;

    for (int k0 = 0; k0 < K; k0 += 32) {
#pragma unroll
        for (int it = 0; it < 4; ++it) {
            int id = tid + 256 * it;
            int r = id >> 3, c4 = id & 7;
            float4 av;
            if constexpr (AZ) {
                size_t idx = (size_t)(m0 + r) * K + k0 + c4 * 4;
                float4 m4 = *(const float4*)(ZMU + idx);
                float4 l4 = *(const float4*)(ZLV + idx);
                float4 e4 = *(const float4*)(ZEP + idx);
                av.x = m4.x + e4.x * expf(0.5f * l4.x);
                av.y = m4.y + e4.y * expf(0.5f * l4.y);
                av.z = m4.z + e4.z * expf(0.5f * l4.z);
                av.w = m4.w + e4.w * expf(0.5f * l4.w);
            } else {
                av = *(const float4*)(A + (size_t)(m0 + r) * K + k0 + c4 * 4);
            }
            float4 wv = *(const float4*)(W + (size_t)(n0 + r) * K + k0 + c4 * 4);
            As[c4*4+0][r] = av.x; As[c4*4+1][r] = av.y; As[c4*4+2][r] = av.z; As[c4*4+3][r] = av.w;
            Ws[c4*4+0][r] = wv.x; Ws[c4*4+1][r] = wv.y; Ws[c4*4+2][r] = wv.z; Ws[c4*4+3][r] = wv.w;
        }
        __syncthreads();
#pragma unroll
        for (int k = 0; k < 32; ++k) {
            float4 a0 = *(const float4*)&As[k][ty*8];
            float4 a1 = *(const float4*)&As[k][ty*8+4];
            float4 w0 = *(const float4*)&Ws[k][tx*8];
            float4 w1 = *(const float4*)&Ws[k][tx*8+4];
            float ar[8] = {a0.x,a0.y,a0.z,a0.w,a1.x,a1.y,a1.z,a1.w};
            float wr[8] = {w0.x,w0.y,w0.z,w0.w,w1.x,w1.y,w1.z,w1.w};
#pragma unroll
            for (int i = 0; i < 8; ++i)
#pragma unroll
                for (int j = 0; j < 8; ++j) acc[i][j] += ar[i] * wr[j];
        }
        __syncthreads();
    }
#pragma unroll
    for (int i = 0; i < 8; ++i) {
        size_t m = (size_t)m0 + ty*8 + i;
#pragma unroll
        for (int j4 = 0; j4 < 2; ++j4) {
            float o[4];
#pragma unroll
            for (int j = 0; j < 4; ++j) {
                int col = n0 + tx*8 + j4*4 + j;
                float v = acc[i][j4*4+j];
                if (svec) v *= svec[col];
                v += tvec[col];
                if constexpr (EPI == 1) v = fmaxf(v, 0.f);
                if constexpr (EPI == 2) v = fminf(fmaxf(v, -10.f), 10.f);
                if constexpr (EPI == 3) v = expf(v);
                o[j] = v;
            }
            *(float4*)(C + m * N + n0 + tx*8 + j4*4) = *(float4*)o;
        }
    }
}

// ============ cross-block exchange: relaxed agent atomics, NO fences ============
// Padded counters (256B/line each) kill the round-8 LLC line-contention: 16
// counters shared one 64B line -> ~192 serialized RMW owner-transfers per step.
// Poll is a relaxed agent LOAD (read-shared line, no exclusive ownership);
// the single fetch_add remains the signal. Data stores/loads proven fresh
// (round-8 passed with exactly these load/store ops).
__device__ __forceinline__ void xstore(float* p, float v) {
    __hip_atomic_store(p, v, __ATOMIC_RELAXED, __HIP_MEMORY_SCOPE_AGENT);
}
__device__ __forceinline__ float xload(const float* p) {
    return __hip_atomic_load(p, __ATOMIC_RELAXED, __HIP_MEMORY_SCOPE_AGENT);
}
__device__ __forceinline__ void xsync(unsigned* cb, unsigned tgt) {
    asm volatile("s_waitcnt vmcnt(0)" ::: "memory");
    __hip_atomic_fetch_add(cb, 1u, __ATOMIC_RELAXED, __HIP_MEMORY_SCOPE_AGENT);
    int guard = 0;
    while (__hip_atomic_load(cb, __ATOMIC_RELAXED, __HIP_MEMORY_SCOPE_AGENT) < tgt) {
        __builtin_amdgcn_s_sleep(2);
        if (++guard > (1 << 17)) break;   // bounded: fails measurably, not a hang
    }
    asm volatile("" ::: "memory");
}

// ---------------- scan layer 0: 256 blocks (4 per batch), 256 threads ----------------
__global__ __launch_bounds__(256)
__attribute__((amdgpu_waves_per_eu(1, 1)))
void k_scan0(const float* gi0, const float* wh0, const float* bhh0,
             const float* lg0, const float* lb0,
             float* h0s, float* xbuf, unsigned* cnt)
{
    const int xcd  = blockIdx.x & 7;
    const int slot = blockIdx.x >> 3;       // 0..31
    const int b    = xcd * 8 + (slot >> 2); // 4 blocks of b land on one XCD
    const int q    = slot & 3;
    const int tid = threadIdx.x;
    const int lane = tid & 63;
    const int wvi  = tid >> 6;

    __shared__ float s_h[256];
    __shared__ float s_g[192];
    __shared__ float s_r1[4], s_r2[4];

    int row = 0;
    if (tid < 192)
        row = (tid < 64) ? (64*q + tid)
            : (tid < 128) ? (256 + 64*q + (tid-64))
                          : (512 + 64*q + (tid-128));
    float4 wr[64];
    float bA = 0.f;
    if (tid < 192) {
        const float4* p = (const float4*)(wh0 + (size_t)row * 256);
#pragma unroll
        for (int i = 0; i < 64; ++i) wr[i] = p[i];
        bA = bhh0[row];
    }
    const float gv = lg0[tid], bv = lb0[tid];
    s_h[tid] = 0.f;
    __syncthreads();

    const float* gbase = gi0 + (size_t)b * 1024 * 768;
    float* hb = h0s + (size_t)b * 1024 * 256;
    unsigned* cb = cnt + (size_t)b * CNT_STRIDE;

    for (int t = 0; t < 1024; ++t) {
        float gr = 0.f, gz = 0.f, gn = 0.f;
        if (tid >= 192) {               // wave 3: issue gi0 loads under waves 0-2's dots
            const float* gt = gbase + (size_t)t * 768;
            int u = 64*q + (tid - 192);
            gr = gt[u]; gz = gt[256 + u]; gn = gt[512 + u];
        } else {
            // frozen round-4 dot: groups ascending, x->a0 y->a1 z->a2 w->a3, (a0+a1)+(a2+a3)
            float a0 = bA, a1 = 0.f, a2 = 0.f, a3 = 0.f;
            const float4* H = (const float4*)s_h;
#pragma unroll
            for (int i = 0; i < 64; ++i) {
                float4 h4 = H[i];
                a0 += wr[i].x * h4.x; a1 += wr[i].y * h4.y;
                a2 += wr[i].z * h4.z; a3 += wr[i].w * h4.w;
            }
            s_g[tid] = (a0 + a1) + (a2 + a3);
        }
        __syncthreads();                                  // B1
        float* xw = xbuf + (((size_t)b * 2 + (t & 1)) * 4 + q) * 64;
        if (tid >= 192) {
            int g = tid - 192;
            int u = 64*q + g;
            float r  = 1.f / (1.f + expf(-(gr + s_g[g])));
            float zg = 1.f / (1.f + expf(-(gz + s_g[64 + g])));
            float nn = tanhf(gn + r * s_g[128 + g]);
            float hn = (1.f - zg) * nn + zg * s_h[u];
            xstore(&xw[g], hn);
        }
        __syncthreads();                                  // B2: drains all waves' stores
        if (tid == 0) xsync(cb, 4u * (unsigned)(t + 1));
        __syncthreads();                                  // B3
        const float* xr = xbuf + (((size_t)b * 2 + (t & 1)) * 4) * 64;
        float hn = xload(&xr[tid]);
        float sum = hn;
#pragma unroll
        for (int o = 32; o > 0; o >>= 1) sum += __shfl_xor(sum, o);
        if (lane == 0) s_r1[wvi] = sum;
        __syncthreads();
        float m = (s_r1[0] + s_r1[1] + s_r1[2] + s_r1[3]) * (1.f / 256.f);
        float d = hn - m;
        float ss = d * d;
#pragma unroll
        for (int o = 32; o > 0; o >>= 1) ss += __shfl_xor(ss, o);
        if (lane == 0) s_r2[wvi] = ss;
        __syncthreads();
        float va = (s_r2[0] + s_r2[1] + s_r2[2] + s_r2[3]) * (1.f / 256.f);
        float rs = 1.f / sqrtf(va + 1e-5f);
        float hl = d * rs * gv + bv;
        s_h[tid] = hl;
        if (q == 0) hb[(size_t)t * 256 + tid] = hl;
        __syncthreads();                                  // B4
    }
}

// ---------------- scan layer 1: 256 blocks (4 per batch), 256 threads ----------------
__global__ __launch_bounds__(256)
__attribute__((amdgpu_waves_per_eu(1, 1)))
void k_scan1(const float* h0s, const float* wi1, const float* wh1,
             const float* bih1, const float* bhh1,
             const float* lg1, const float* lb1,
             const float* fcW, const float* fcb,
             float* vout, float* xbuf, unsigned* cnt)
{
    const int xcd  = blockIdx.x & 7;
    const int slot = blockIdx.x >> 3;
    const int b    = xcd * 8 + (slot >> 2);
    const int q    = slot & 3;
    const int tid = threadIdx.x;
    const int lane = tid & 63;
    const int wvi  = tid >> 6;

    __shared__ float s_x[256];
    __shared__ float s_h[128];
    __shared__ float s_gi[96];
    __shared__ float s_gh[96];
    __shared__ float s_r1[2], s_r2[2];

    float4 wr[64];
    float bB = 0.f;
    if (tid < 96) {
        int jj = tid;
        int row = (jj < 32) ? (32*q + jj) : (jj < 64) ? (128 + 32*q + (jj-32)) : (256 + 32*q + (jj-64));
        const float4* p = (const float4*)(wi1 + (size_t)row * 256);
#pragma unroll
        for (int i = 0; i < 64; ++i) wr[i] = p[i];
        bB = bih1[row];
    } else if (tid < 192) {
        int jj = tid - 96;
        int row = (jj < 32) ? (32*q + jj) : (jj < 64) ? (128 + 32*q + (jj-32)) : (256 + 32*q + (jj-64));
        const float4* p = (const float4*)(wh1 + (size_t)row * 128);
#pragma unroll
        for (int i = 0; i < 32; ++i) wr[i] = p[i];
        bB = bhh1[row];
    }
    float gv = 0.f, bv = 0.f;
    if (tid < 128) { gv = lg1[tid]; bv = lb1[tid]; s_h[tid] = 0.f; }
    const float4* xb4 = (const float4*)(h0s + (size_t)b * 1024 * 256);
    if (tid < 64) ((float4*)s_x)[tid] = xb4[tid];         // stage t=0
    __syncthreads();

    unsigned* cb = cnt + (size_t)b * CNT_STRIDE;

    for (int t = 0; t < 1024; ++t) {
        if (tid < 96) {
            float a0 = bB, a1 = 0.f, a2 = 0.f, a3 = 0.f;
            const float4* X = (const float4*)s_x;
#pragma unroll
            for (int i = 0; i < 64; ++i) {
                float4 h4 = X[i];
                a0 += wr[i].x * h4.x; a1 += wr[i].y * h4.y;
                a2 += wr[i].z * h4.z; a3 += wr[i].w * h4.w;
            }
            s_gi[tid] = (a0 + a1) + (a2 + a3);
        } else if (tid < 192) {
            float a0 = bB, a1 = 0.f, a2 = 0.f, a3 = 0.f;
            const float4* Hh = (const float4*)s_h;
#pragma unroll
            for (int i = 0; i < 32; ++i) {
                float4 h4 = Hh[i];
                a0 += wr[i].x * h4.x; a1 += wr[i].y * h4.y;
                a2 += wr[i].z * h4.z; a3 += wr[i].w * h4.w;
            }
            s_gh[tid - 96] = (a0 + a1) + (a2 + a3);
        }
        __syncthreads();                                  // B1
        float* xw = xbuf + (((size_t)b * 2 + (t & 1)) * 4 + q) * 32;
        if (tid >= 192 && tid < 224) {
            int g = tid - 192;
            int u = 32*q + g;
            float r  = 1.f / (1.f + expf(-(s_gi[g]      + s_gh[g])));
            float zg = 1.f / (1.f + expf(-(s_gi[32 + g] + s_gh[32 + g])));
            float nn = tanhf(s_gi[64 + g] + r * s_gh[64 + g]);
            float hn = (1.f - zg) * nn + zg * s_h[u];
            xstore(&xw[g], hn);
        } else if (tid >= 224 && t + 1 < 1024) {          // stage s_x(t+1) under gates
            int k = tid - 224;
            ((float4*)s_x)[k]      = xb4[(size_t)(t+1) * 64 + k];
            ((float4*)s_x)[k + 32] = xb4[(size_t)(t+1) * 64 + k + 32];
        }
        __syncthreads();                                  // B2
        if (tid == 0) xsync(cb, 4u * (unsigned)(t + 1));
        __syncthreads();                                  // B3
        const float* xr = xbuf + (((size_t)b * 2 + (t & 1)) * 4) * 32;
        float hn = 0.f, d = 0.f;
        if (tid < 128) {
            hn = xload(&xr[tid]);
            float sum = hn;
#pragma unroll
            for (int o = 32; o > 0; o >>= 1) sum += __shfl_xor(sum, o);
            if (lane == 0) s_r1[wvi] = sum;
        }
        __syncthreads();
        if (tid < 128) {
            float m = (s_r1[0] + s_r1[1]) * (1.f / 128.f);
            d = hn - m;
            float ss = d * d;
#pragma unroll
            for (int o = 32; o > 0; o >>= 1) ss += __shfl_xor(ss, o);
            if (lane == 0) s_r2[wvi] = ss;
        }
        __syncthreads();
        if (tid < 128) {
            float va = (s_r2[0] + s_r2[1]) * (1.f / 128.f);
            float rs = 1.f / sqrtf(va + 1e-5f);
            float hl = d * rs * gv + bv;
            s_h[tid] = hl;
        }
        __syncthreads();                                  // B4
    }
    float p0 = 0.f, p1 = 0.f;
    if (tid < 128) {
        float hold = s_h[tid];
        p0 = fcW[tid] * hold;
        p1 = fcW[128 + tid] * hold;
#pragma unroll
        for (int o = 32; o > 0; o >>= 1) { p0 += __shfl_xor(p0, o); p1 += __shfl_xor(p1, o); }
        if (lane == 0) { s_r1[wvi] = p0; s_r2[wvi] = p1; }
    }
    __syncthreads();
    if (tid == 0 && q == 0) {
        vout[b * 2 + 0] = s_r1[0] + s_r1[1] + fcb[0];
        vout[b * 2 + 1] = s_r2[0] + s_r2[1] + fcb[1];
    }
}

// ---------------- launcher ----------------
extern "C" void kernel_launch(void* const* d_in, const int* in_sizes, int n_in,
                              void* d_out, int out_size, void* d_ws, size_t ws_size,
                              hipStream_t stream)
{
    const float* x     = (const float*)d_in[0];
    const float* eps   = (const float*)d_in[1];
    const float* W1lv  = (const float*)d_in[2];
    const float* b1lv  = (const float*)d_in[3];
    const float* W2lv  = (const float*)d_in[4];
    const float* b2lv  = (const float*)d_in[5];
    const float* Wmu   = (const float*)d_in[6];
    const float* bmu   = (const float*)d_in[7];
    const float* bn_g  = (const float*)d_in[8];
    const float* bn_b  = (const float*)d_in[9];
    const float* bn_rm = (const float*)d_in[10];
    const float* bn_rv = (const float*)d_in[11];
    const float* Wdec  = (const float*)d_in[12];
    const float* bdec  = (const float*)d_in[13];
    const float* Wih0  = (const float*)d_in[14];
    const float* Whh0  = (const float*)d_in[15];
    const float* bih0  = (const float*)d_in[16];
    const float* bhh0  = (const float*)d_in[17];
    const float* Wih1  = (const float*)d_in[18];
    const float* Whh1  = (const float*)d_in[19];
    const float* bih1  = (const float*)d_in[20];
    const float* bhh1  = (const float*)d_in[21];
    const float* ln_g0 = (const float*)d_in[22];
    const float* ln_b0 = (const float*)d_in[23];
    const float* ln_g1 = (const float*)d_in[24];
    const float* ln_b1 = (const float*)d_in[25];
    const float* fc_W  = (const float*)d_in[26];
    const float* fc_b  = (const float*)d_in[27];

    float* out   = (float*)d_out;
    float* v_out = out;                                   // [64,2]
    float* xrec  = out + 128;                             // [64,1024,256]
    float* mu    = out + 128 + 16777216;                  // [64,1024,128]
    float* lv    = out + 128 + 16777216 + 8388608;        // [64,1024,128]
    float* H0S   = xrec;  // h0 stream parked in xrec slot; decoder overwrites after scan1

    if (ws_size < WS_NEED) return;  // distinctive failure: outputs stay zero
    char* ws = (char*)d_ws;
    float*    XL    = (float*)(ws + WS_XL);
    float*    HENC  = (float*)(ws + WS_HENC);
    float*    GI0   = (float*)(ws + WS_GI0);    // overlays XL+HENC (dead by then)
    float*    XBUF0 = (float*)(ws + WS_XBUF0);
    float*    XBUF1 = (float*)(ws + WS_XBUF1);
    unsigned* CNT0  = (unsigned*)(ws + WS_CNT);
    unsigned* CNT1  = CNT0 + 64 * CNT_STRIDE;
    float*    MUS   = (float*)(ws + WS_MUS);
    float*    MUT   = (float*)(ws + WS_MUT);

    k_prep<<<1, 128, 0, stream>>>(bmu, bn_g, bn_b, bn_rm, bn_rv, MUS, MUT);
    k_xl<<<16384, 256, 0, stream>>>(x, XL, 4194304);
    // encoder
    k_gemm_f32<1,0><<<dim3(512, 4), 256, 0, stream>>>(XL,   W1lv, nullptr, b1lv, HENC, 512, 256, nullptr, nullptr, nullptr);
    k_gemm_f32<0,0><<<dim3(512, 1), 256, 0, stream>>>(HENC, W2lv, nullptr, b2lv, lv,   128, 512, nullptr, nullptr, nullptr);
    k_gemm_f32<2,0><<<dim3(512, 1), 256, 0, stream>>>(XL,   Wmu,  MUS,     MUT,  mu,   128, 256, nullptr, nullptr, nullptr);
    // gi0 GEMM with fused reparameterization (XL/HENC dead -> GI0 overlays them)
    k_gemm_f32<0,1><<<dim3(512, 6), 256, 0, stream>>>(nullptr, Wih0, nullptr, bih0, GI0, 768, 128, mu, lv, eps);
    // reset exchange counters (per launch, graph-capture-safe)
    hipMemsetAsync(CNT0, 0, 32768, stream);
    // sequential scans (4 blocks per batch row, full weight residency)
    k_scan0<<<256, 256, 0, stream>>>(GI0, Whh0, bhh0, ln_g0, ln_b0, H0S, XBUF0, CNT0);
    k_scan1<<<256, 256, 0, stream>>>(H0S, Wih1, Whh1, bih1, bhh1, ln_g1, ln_b1, fc_W, fc_b, v_out, XBUF1, CNT1);
    // decoder with fused reparameterization (overwrites H0S parking with final xrec)
    k_gemm_f32<3,1><<<dim3(512, 2), 256, 0, stream>>>(nullptr, Wdec, nullptr, bdec, xrec, 256, 128, mu, lv, eps);
}